// Round 8
// baseline (228.119 us; speedup 1.0000x reference)
//
#include <hip/hip_runtime.h>

#define NIN   55296
#define CIN   256
#define COUT  256
#define NTH   256
#define NBLK  864   // 2 parities * 432 tiles of 128 rows

typedef __attribute__((ext_vector_type(8))) _Float16 half8;
typedef __attribute__((ext_vector_type(4))) _Float16 half4;
typedef __attribute__((ext_vector_type(4))) float f32x4;

typedef const __attribute__((address_space(1))) void* gp_t;
typedef __attribute__((address_space(3))) void* lp_t;
__device__ __forceinline__ void gload16(const void* g, char* l) {
  __builtin_amdgcn_global_load_lds((gp_t)g, (lp_t)l, 16, 0, 0);
}

// ---------- pre-pass: features f32 -> f16 ----------
__global__ void k_feat_cvt(const float* __restrict__ f, _Float16* __restrict__ o, int n4) {
  int i = blockIdx.x * blockDim.x + threadIdx.x;
  if (i >= n4) return;
  f32x4 v = ((const f32x4*)f)[i];
  half4 r;
  r[0] = (_Float16)v[0]; r[1] = (_Float16)v[1];
  r[2] = (_Float16)v[2]; r[3] = (_Float16)v[3];
  ((half4*)o)[i] = r;
}

// ---------- pre-pass: W f32 [27][cin][cout] -> f16 transposed Wt [27][cout][cin]
__global__ void k_w_cvt(const float* __restrict__ W, _Float16* __restrict__ Wt,
                        float* __restrict__ zeros) {
  int i = blockIdx.x * blockDim.x + threadIdx.x;
  int d   = i >> 16;
  int rem = i & 65535;
  int n   = rem >> 8;
  int k   = rem & 255;
  Wt[i] = (_Float16)W[(d << 16) + (k << 8) + n];
  if (blockIdx.x == 0 && threadIdx.x < 128) zeros[threadIdx.x] = 0.0f;
}

// ---------- main: 4-wave 128x256 tile, BK=32, dbuf LDS, 2 blocks/CU ----------
// The structural lever vs rounds 3-7: TWO independent workgroups per CU, so one
// block's barrier/drain bubbles are hidden by the other block's compute (m114).
// LDS (49664 B): buf d at d*24576: A [128 rows][64B] @+0, B [256 couts][64B] @+8192.
// orow @49152. Per step: __syncthreads (vmcnt(0) drain -- hidden by sibling block)
//   -> issue 6 DMA gloads (next step) -> 12 ds_reads -> 32 MFMA (nf-outer so b[nf]
//   drains progressively under MFMA). Swizzle: pre-swizzled global source + linear
//   LDS dest (m173); read side applies the same XOR (involution).
__global__ __launch_bounds__(NTH, 2)
void k_conv4(const _Float16* __restrict__ featb, const _Float16* __restrict__ wt,
             const char* __restrict__ zeros, float* __restrict__ out) {
  extern __shared__ char lds[];
  int* orow = (int*)(lds + 49152);

  const int braw = blockIdx.x;
  const int b    = (braw & 7) * 108 + (braw >> 3); // bijective XCD swizzle (864 = 8*108)
  const int p    = b & 1;                           // output-voxel parity
  const int tile = b >> 1;                          // 0..431 (128 rows each)

  const int tid = threadIdx.x;
  const int w   = tid >> 6;                         // wave 0..3
  const int l   = tid & 63;

  // ---- staging geometry: pass covers 64 rows (4 waves x 16); lane l -> local row
  // w*16+(l>>2), slot (l&3) XOR-swizzled. LDS dest stays linear (wave base + l*16).
  const int swz = ((l & 3) ^ ((l >> 3) & 3)) * 16;  // key = ((row&15)>>1)&3
  const int lrow = w * 16 + (l >> 2);               // [0,64) per pass

  int xs[2], ys[2], zs[2];
#pragma unroll
  for (int q = 0; q < 2; ++q) {                     // A pass q: rows q*64 + lrow
    int e  = tile * 128 + q * 64 + lrow;
    int c  = e / 24;
    int zi = e - c * 24;
    int x  = c / 48;
    int y  = c - x * 48;
    xs[q] = x; ys[q] = y; zs[q] = 2 * zi + ((x + y + p) & 1);
  }
  const char* wtc   = (const char*)wt;
  const char* featc = (const char*)featb;
  const int brow = lrow * 512 + swz;                // B pass q: +q*64*512

  // ---- fragment-read geometry: wave grid 2x2 (Mw=64, Nw=128) ----
  const int wm = w >> 1, wn = w & 1;
  const int lr = l & 15, kg = l >> 4;
  const int rsw = (kg ^ ((lr >> 1) & 3)) * 16;      // read-side swizzle (matches store)
  const int aRd = (wm * 64 + lr) * 64 + rsw;
  const int bRd = 8192 + (wn * 128 + lr) * 64 + rsw;

  // ---- orow table (visible after first __syncthreads) ----
  if (tid < 128) {
    int e = tile * 128 + tid;
    int c = e / 24;
    int zi = e - c * 24;
    int x = c / 48;
    int y = c - x * 48;
    int z = 2 * zi + ((x + y + p) & 1);
    orow[tid] = (x * 48 + y) * 48 + z;
  }

  // ---- offset state (prefetch side) ----
  const char* asrc[2];
  const char* wtile;
  auto setoff = [&](int d27) {
    int dx = d27 / 9 - 1, dy = (d27 / 3) % 3 - 1, dz = d27 % 3 - 1;
#pragma unroll
    for (int q = 0; q < 2; ++q) {
      int ux = xs[q] + dx, uy = ys[q] + dy, uz = zs[q] + dz;
      bool v = (unsigned)ux < 48u && (unsigned)uy < 48u && (unsigned)uz < 48u;
      int idx = (ux * 48 + uy) * 24 + (uz >> 1);    // analytic even-lattice row id
      asrc[q] = (v ? (featc + idx * 512) : zeros) + swz;
    }
    wtile = wtc + d27 * 131072;
  };

  const int pb = p ? 0 : 1;                         // first offset with sum-parity p
  setoff(pb);

  // ---- prologue: stage step 0 into buf 0 (6 gloads: A q0,q1 + B q0..q3) ----
  gload16(asrc[0],               lds + 0    + w * 1024);
  gload16(asrc[1],               lds + 4096 + w * 1024);
  gload16(wtile + brow,          lds + 8192 + w * 1024);
  gload16(wtile + brow + 32768,  lds + 12288 + w * 1024);
  gload16(wtile + brow + 65536,  lds + 16384 + w * 1024);
  gload16(wtile + brow + 98304,  lds + 20480 + w * 1024);

  f32x4 acc[4][8];
#pragma unroll
  for (int i = 0; i < 4; ++i)
#pragma unroll
    for (int j = 0; j < 8; ++j) acc[i][j] = (f32x4)0.0f;

  const int S = p ? 112 : 104;                      // (14 or 13 offsets) * 8 K-steps

  for (int s = 0; s < S; ++s) {
    __syncthreads();  // vmcnt(0): DMA into buf d landed; d^1 readers done (sibling block hides the drain)

    const char* Ab = lds + (s & 1) * 24576;

    // ---- issue next-step staging into buf d^1 ----
    const int sn = s + 1;
    if (sn < S) {
      if ((sn & 7) == 0) setoff(pb + ((sn >> 3) << 1));
      const int kb = (sn & 7) * 64;
      char* Nb = lds + (sn & 1) * 24576;
      gload16(asrc[0] + kb,              Nb + 0    + w * 1024);
      gload16(asrc[1] + kb,              Nb + 4096 + w * 1024);
      gload16(wtile + brow + kb,         Nb + 8192 + w * 1024);
      gload16(wtile + brow + kb + 32768, Nb + 12288 + w * 1024);
      gload16(wtile + brow + kb + 65536, Nb + 16384 + w * 1024);
      gload16(wtile + brow + kb + 98304, Nb + 20480 + w * 1024);
    }

    // ---- 12 ds_reads (counted lgkm: drain under MFMA) ----
    half8 a[4], bf[8];
#pragma unroll
    for (int mf = 0; mf < 4; ++mf) a[mf] = *(const half8*)(Ab + aRd + mf * 1024);
#pragma unroll
    for (int nf = 0; nf < 8; ++nf) bf[nf] = *(const half8*)(Ab + bRd + nf * 1024);
    __builtin_amdgcn_sched_barrier(0);

    // ---- 32 MFMA, nf-outer so bf[nf] is needed progressively ----
    __builtin_amdgcn_s_setprio(1);
#pragma unroll
    for (int nf = 0; nf < 8; ++nf)
#pragma unroll
      for (int mf = 0; mf < 4; ++mf)
        acc[mf][nf] = __builtin_amdgcn_mfma_f32_16x16x32_f16(a[mf], bf[nf], acc[mf][nf], 0, 0, 0);
    __builtin_amdgcn_s_setprio(0);
  }

  // ---- epilogue: C/D layout col=lane&15, row=(lane>>4)*4+i ----
#pragma unroll
  for (int mf = 0; mf < 4; ++mf) {
#pragma unroll
    for (int i = 0; i < 4; ++i) {
      int r = wm * 64 + mf * 16 + kg * 4 + i;
      int o = orow[r];
      float* dst = out + (size_t)o * COUT + wn * 128 + lr;
#pragma unroll
      for (int nf = 0; nf < 8; ++nf) dst[nf * 16] = acc[mf][nf][i];
    }
  }
}

extern "C" void kernel_launch(void* const* d_in, const int* in_sizes, int n_in,
                              void* d_out, int out_size, void* d_ws, size_t ws_size,
                              hipStream_t stream) {
  const float* features = (const float*)d_in[0];
  const float* W = (const float*)d_in[3];
  float* out = (float*)d_out;

  char* ws = (char*)d_ws;
  _Float16* featb = (_Float16*)ws;                      // 28,311,552 B
  _Float16* Wt    = (_Float16*)(ws + 28311552);         //  3,538,944 B
  float*    zeros = (float*)(ws + 28311552 + 3538944);  //       512 B

  (void)hipFuncSetAttribute(reinterpret_cast<const void*>(k_conv4),
                            hipFuncAttributeMaxDynamicSharedMemorySize, 49664);

  {
    int n4 = NIN * CIN / 4;
    k_feat_cvt<<<(n4 + 255) / 256, 256, 0, stream>>>(features, featb, n4);
  }
  k_w_cvt<<<27 * 65536 / 256, 256, 0, stream>>>(W, Wt, zeros);

  k_conv4<<<NBLK, NTH, 49664, stream>>>(featb, Wt, (const char*)zeros, out);
}

// Round 10
// 217.897 us; speedup vs baseline: 1.0469x; 1.0469x over previous
//
#include <hip/hip_runtime.h>

#define NIN   55296
#define CIN   256
#define COUT  256
#define NTH   512
#define NBLK  432   // 2 parities * 216 tiles of 256 rows

typedef __attribute__((ext_vector_type(8))) _Float16 half8;
typedef __attribute__((ext_vector_type(4))) _Float16 half4;
typedef __attribute__((ext_vector_type(4))) float f32x4;

typedef const __attribute__((address_space(1))) void* gp_t;
typedef __attribute__((address_space(3))) void* lp_t;
__device__ __forceinline__ void gload16(const void* g, char* l) {
  __builtin_amdgcn_global_load_lds((gp_t)g, (lp_t)l, 16, 0, 0);
}

#define VM4 asm volatile("s_waitcnt vmcnt(4)" ::: "memory")
#define VM0 asm volatile("s_waitcnt vmcnt(0)" ::: "memory")
#define LG0 do { asm volatile("s_waitcnt lgkmcnt(0)" ::: "memory"); \
                 __builtin_amdgcn_sched_barrier(0); } while (0)
#define BAR __builtin_amdgcn_s_barrier()

// ---------- pre-pass: features f32 -> f16 ----------
__global__ void k_feat_cvt(const float* __restrict__ f, _Float16* __restrict__ o, int n4) {
  int i = blockIdx.x * blockDim.x + threadIdx.x;
  if (i >= n4) return;
  f32x4 v = ((const f32x4*)f)[i];
  half4 r;
  r[0] = (_Float16)v[0]; r[1] = (_Float16)v[1];
  r[2] = (_Float16)v[2]; r[3] = (_Float16)v[3];
  ((half4*)o)[i] = r;
}

// ---------- pre-pass: W f32 [27][cin][cout] -> f16 transposed Wt [27][cout][cin]
__global__ void k_w_cvt(const float* __restrict__ W, _Float16* __restrict__ Wt,
                        float* __restrict__ zeros) {
  int i = blockIdx.x * blockDim.x + threadIdx.x;
  int d   = i >> 16;
  int rem = i & 65535;
  int n   = rem >> 8;
  int k   = rem & 255;
  Wt[i] = (_Float16)W[(d << 16) + (k << 8) + n];
  if (blockIdx.x == 0 && threadIdx.x < 128) zeros[threadIdx.x] = 0.0f;
}

// ---------- main: 8-wave 256x256 tile, BK=64, m201-style 4-phase/K-tile ----------
// LDS slot s=t&1 at s*65536: A-half0 {mf0-3 rows} (ks0 @+0, ks1 @+8192),
//   A-half1 {mf4-7} @+16384/+24576, B-half0 {nf0-1 couts} @+32768/+40960,
//   B-half1 {nf2-3} @+49152/+57344. orow @131072.
// Stage order per tile t (for t+1): P0:A0, P1:B0, P2:B1, P3:A1 (2 gloads each).
// Consumption: A0,B0 @P0; B1 @P1; A1 @P2. vmcnt(4) at P0/P1/P3 (never 0 in loop).
// Ledger (per wave, steady state): before P0 wait queue=[A1(t)x2, A0(t+1)x2]+...
//   each phase's ds_reads are covered by the PREVIOUS phase's vmcnt(4)+barrier.
// CRITICAL (r9 bug): tile 0's P0 has no predecessor -> the prologue must drain
//   vmcnt to 4 (A0,B0 landed) + barrier BEFORE the loop's first ds_reads.
__global__ __launch_bounds__(NTH, 2)
void k_conv8(const _Float16* __restrict__ featb, const _Float16* __restrict__ wt,
             const char* __restrict__ zeros, float* __restrict__ out) {
  extern __shared__ char lds[];
  int* orow = (int*)(lds + 131072);

  const int braw = blockIdx.x;
  const int b    = (braw & 7) * 54 + (braw >> 3);   // bijective XCD swizzle (432 = 8*54)
  const int p    = b & 1;                            // output-voxel parity
  const int tile = b >> 1;                           // 0..215

  const int tid   = threadIdx.x;
  const int w     = tid >> 6;
  const int l     = tid & 63;
  const int tid16 = tid * 16;

  // ---- staging geometry: thread covers 16B slot of a [128 rows][64B] half-block
  const int r4   = tid >> 2;                         // row/cout within half, 0..127
  const int swz  = ((tid & 3) ^ ((tid >> 3) & 3)) * 16;  // slot XOR, key=(row>>1)&3

  // A coords: half h holds global rows (r4>>6)*128 + h*64 + (r4&63)
  int xs[2], ys[2], zs[2];
#pragma unroll
  for (int h = 0; h < 2; ++h) {
    int e  = tile * 256 + (r4 >> 6) * 128 + h * 64 + (r4 & 63);
    int c  = e / 24;
    int zi = e - c * 24;
    int x  = c / 48;
    int y  = c - x * 48;
    xs[h] = x; ys[h] = y; zs[h] = 2 * zi + ((x + y + p) & 1);
  }
  const char* wtc   = (const char*)wt;
  const char* featc = (const char*)featb;
  // B: half h holds couts (r4>>5)*64 + h*32 + (r4&31)
  const int bro0 = (((r4 >> 5) * 64) + (r4 & 31)) * 512 + swz;
  const int bro1 = bro0 + 32 * 512;

  // ---- fragment-read geometry ----
  const int wm = w >> 2, wn = w & 3;
  const int lr = l & 15, kg = l >> 4;
  const int rsw  = (kg ^ ((lr >> 1) & 3)) * 16;      // read-side swizzle (involution)
  const int arow = (wm * 64 + lr) * 64 + rsw;        // + mf*1024 (+16384 for half1)
  const int brd  = (wn * 32 + lr) * 64 + rsw;        // + (nf&1)*1024, B-half via +16384

  // ---- orow table (read only in epilogue) ----
  if (tid < 256) {
    int e = tile * 256 + tid;
    int c = e / 24;
    int zi = e - c * 24;
    int x = c / 48;
    int y = c - x * 48;
    int z = 2 * zi + ((x + y + p) & 1);
    orow[tid] = (x * 48 + y) * 48 + z;
  }

  // ---- offset state (staging side) ----
  const char* asrc[2];
  const char* wtile;
  auto setoff = [&](int d27) {
    int dx = d27 / 9 - 1, dy = (d27 / 3) % 3 - 1, dz = d27 % 3 - 1;
#pragma unroll
    for (int h = 0; h < 2; ++h) {
      int ux = xs[h] + dx, uy = ys[h] + dy, uz = zs[h] + dz;
      bool v = (unsigned)ux < 48u && (unsigned)uy < 48u && (unsigned)uz < 48u;
      int idx = (ux * 48 + uy) * 24 + (uz >> 1);     // analytic even-lattice row id
      asrc[h] = (v ? (featc + idx * 512) : zeros) + swz;
    }
    wtile = wtc + d27 * 131072;
  };

  const int pb = p ? 0 : 1;
  int pn = pb;
  setoff(pn);

  // ---- prologue: stage tile 0 in ledger order A0,B0,B1,A1 (koff=0) ----
  gload16(asrc[0],           lds + tid16);           // A0 ks0
  gload16(asrc[0] + 64,      lds + 8192  + tid16);   // A0 ks1
  gload16(wtile + bro0,      lds + 32768 + tid16);   // B0 ks0
  gload16(wtile + bro0 + 64, lds + 40960 + tid16);   // B0 ks1
  gload16(wtile + bro1,      lds + 49152 + tid16);   // B1 ks0
  gload16(wtile + bro1 + 64, lds + 57344 + tid16);   // B1 ks1
  gload16(asrc[1],           lds + 16384 + tid16);   // A1 ks0
  gload16(asrc[1] + 64,      lds + 24576 + tid16);   // A1 ks1

  f32x4 acc[8][4];
#pragma unroll
  for (int i = 0; i < 8; ++i)
#pragma unroll
    for (int j = 0; j < 4; ++j) acc[i][j] = (f32x4)0.0f;

  // ---- r9 FIX: drain A0/B0 (vmcnt 8->4) + orow ds_write, then barrier, BEFORE
  // the loop's first ds_reads. Leaves B1(0),A1(0) in flight = steady-state entry.
  asm volatile("s_waitcnt lgkmcnt(0)" ::: "memory");
  VM4;
  BAR;

  const int T = p ? 56 : 52;                         // K-tiles: offsets * 4
  int koff = 0;

  for (int t = 0; t < T; ++t) {
    const char* cur = lds + (t & 1) * 65536;
    char*       nxt = lds + ((t + 1) & 1) * 65536;
    const bool  pf  = (t + 1) < T;

    half8 a[4][2], bf[4][2];

    // ================= P0: reads A-half0 + B-half0; stage A0(t+1) =================
#pragma unroll
    for (int m = 0; m < 4; ++m) {
      a[m][0] = *(const half8*)(cur + m * 1024 + arow);
      a[m][1] = *(const half8*)(cur + 8192 + m * 1024 + arow);
    }
#pragma unroll
    for (int n = 0; n < 2; ++n) {
      bf[n][0] = *(const half8*)(cur + 32768 + n * 1024 + brd);
      bf[n][1] = *(const half8*)(cur + 40960 + n * 1024 + brd);
    }
    if (pf) {
      if (((t + 1) & 3) == 0) { pn += 2; setoff(pn); }
      koff = ((t + 1) & 3) * 128;
      gload16(asrc[0] + koff,      nxt + tid16);
      gload16(asrc[0] + koff + 64, nxt + 8192 + tid16);
    }
    if (pf) VM4; else VM0;
    BAR; LG0;
    __builtin_amdgcn_s_setprio(1);
#pragma unroll
    for (int m = 0; m < 4; ++m)
#pragma unroll
      for (int n = 0; n < 2; ++n) {
        acc[m][n] = __builtin_amdgcn_mfma_f32_16x16x32_f16(a[m][0], bf[n][0], acc[m][n], 0, 0, 0);
        acc[m][n] = __builtin_amdgcn_mfma_f32_16x16x32_f16(a[m][1], bf[n][1], acc[m][n], 0, 0, 0);
      }
    __builtin_amdgcn_s_setprio(0);
    BAR;

    // ================= P1: reads B-half1; stage B0(t+1) =================
#pragma unroll
    for (int n = 2; n < 4; ++n) {
      bf[n][0] = *(const half8*)(cur + 49152 + (n & 1) * 1024 + brd);
      bf[n][1] = *(const half8*)(cur + 57344 + (n & 1) * 1024 + brd);
    }
    if (pf) {
      gload16(wtile + bro0 + koff,      nxt + 32768 + tid16);
      gload16(wtile + bro0 + koff + 64, nxt + 40960 + tid16);
    }
    if (pf) VM4; else VM0;
    BAR; LG0;
    __builtin_amdgcn_s_setprio(1);
#pragma unroll
    for (int m = 0; m < 4; ++m)
#pragma unroll
      for (int n = 2; n < 4; ++n) {
        acc[m][n] = __builtin_amdgcn_mfma_f32_16x16x32_f16(a[m][0], bf[n][0], acc[m][n], 0, 0, 0);
        acc[m][n] = __builtin_amdgcn_mfma_f32_16x16x32_f16(a[m][1], bf[n][1], acc[m][n], 0, 0, 0);
      }
    __builtin_amdgcn_s_setprio(0);
    BAR;

    // ================= P2: reads A-half1 (overwrite a); stage B1(t+1) =================
#pragma unroll
    for (int m = 0; m < 4; ++m) {
      a[m][0] = *(const half8*)(cur + 16384 + m * 1024 + arow);
      a[m][1] = *(const half8*)(cur + 24576 + m * 1024 + arow);
    }
    if (pf) {
      gload16(wtile + bro1 + koff,      nxt + 49152 + tid16);
      gload16(wtile + bro1 + koff + 64, nxt + 57344 + tid16);
    }
    BAR; LG0;
    __builtin_amdgcn_s_setprio(1);
#pragma unroll
    for (int m = 0; m < 4; ++m)
#pragma unroll
      for (int n = 0; n < 2; ++n) {
        acc[4 + m][n] = __builtin_amdgcn_mfma_f32_16x16x32_f16(a[m][0], bf[n][0], acc[4 + m][n], 0, 0, 0);
        acc[4 + m][n] = __builtin_amdgcn_mfma_f32_16x16x32_f16(a[m][1], bf[n][1], acc[4 + m][n], 0, 0, 0);
      }
    __builtin_amdgcn_s_setprio(0);
    BAR;

    // ================= P3: no reads; stage A1(t+1) =================
    if (pf) {
      gload16(asrc[1] + koff,      nxt + 16384 + tid16);
      gload16(asrc[1] + koff + 64, nxt + 24576 + tid16);
    }
    if (pf) VM4; else VM0;
    BAR; LG0;
    __builtin_amdgcn_s_setprio(1);
#pragma unroll
    for (int m = 0; m < 4; ++m)
#pragma unroll
      for (int n = 2; n < 4; ++n) {
        acc[4 + m][n] = __builtin_amdgcn_mfma_f32_16x16x32_f16(a[m][0], bf[n][0], acc[4 + m][n], 0, 0, 0);
        acc[4 + m][n] = __builtin_amdgcn_mfma_f32_16x16x32_f16(a[m][1], bf[n][1], acc[4 + m][n], 0, 0, 0);
      }
    __builtin_amdgcn_s_setprio(0);
    BAR;
  }

  // ---- epilogue: C/D layout col=lane&15, row=(lane>>4)*4+i ----
#pragma unroll
  for (int mf = 0; mf < 8; ++mf) {
#pragma unroll
    for (int i = 0; i < 4; ++i) {
      int r = wm * 128 + mf * 16 + kg * 4 + i;
      int o = orow[r];
      float* dst = out + (size_t)o * COUT + wn * 64 + lr;
#pragma unroll
      for (int nf = 0; nf < 4; ++nf) dst[nf * 16] = acc[mf][nf][i];
    }
  }
}

extern "C" void kernel_launch(void* const* d_in, const int* in_sizes, int n_in,
                              void* d_out, int out_size, void* d_ws, size_t ws_size,
                              hipStream_t stream) {
  const float* features = (const float*)d_in[0];
  const float* W = (const float*)d_in[3];
  float* out = (float*)d_out;

  char* ws = (char*)d_ws;
  _Float16* featb = (_Float16*)ws;                      // 28,311,552 B
  _Float16* Wt    = (_Float16*)(ws + 28311552);         //  3,538,944 B
  float*    zeros = (float*)(ws + 28311552 + 3538944);  //       512 B

  (void)hipFuncSetAttribute(reinterpret_cast<const void*>(k_conv8),
                            hipFuncAttributeMaxDynamicSharedMemorySize, 132096);

  {
    int n4 = NIN * CIN / 4;
    k_feat_cvt<<<(n4 + 255) / 256, 256, 0, stream>>>(features, featb, n4);
  }
  k_w_cvt<<<27 * 65536 / 256, 256, 0, stream>>>(W, Wt, zeros);

  k_conv8<<<NBLK, NTH, 132096, stream>>>(featb, Wt, (const char*)zeros, out);
}